// Round 9
// baseline (731.532 us; speedup 1.0000x reference)
//
#include <hip/hip_runtime.h>
#include <stdint.h>

#define LAYERS 6
#define BB 4
#define NSEQ 512
#define DM 768
#define NH 12
#define HD 64
#define DFF 3072
#define MTOK 2048   // B*N
#define QKVN 2304
#define DR1 384
#define TH 72

typedef __attribute__((ext_vector_type(8))) short bf16x8;
typedef __attribute__((ext_vector_type(4))) float f32x4;
typedef __attribute__((ext_vector_type(4))) unsigned int u32x4;

__device__ __forceinline__ unsigned short f2bf(float f) {
  union { float f; uint32_t u; } v; v.f = f;
  return (unsigned short)((v.u + 0x7fffu + ((v.u >> 16) & 1u)) >> 16);
}
__device__ __forceinline__ float bf2f(unsigned short h) {
  union { uint32_t u; float f; } v; v.u = ((uint32_t)h) << 16;
  return v.f;
}
// pack two f32 -> two bf16 (RNE) in one instruction
__device__ __forceinline__ uint32_t pkbf(float lo, float hi) {
  uint32_t r;
  asm("v_cvt_pk_bf16_f32 %0, %1, %2" : "=v"(r) : "v"(lo), "v"(hi));
  return r;
}
__device__ __forceinline__ void gload16(const void* g, void* l) {
  __builtin_amdgcn_global_load_lds((const __attribute__((address_space(1))) void*)g,
                                   (__attribute__((address_space(3))) void*)l, 16, 0, 0);
}
#define MFMA(a, b, c) __builtin_amdgcn_mfma_f32_16x16x32_bf16(a, b, c, 0, 0, 0)

// fast sigmoid(s * 0.125)
__device__ __forceinline__ float sigmoid8(float s) {
  float e, r;
  float t = s * -0.18033688011112443f;
  asm("v_exp_f32 %0, %1" : "=v"(e) : "v"(t));
  float d = 1.0f + e;
  asm("v_rcp_f32 %0, %1" : "=v"(r) : "v"(d));
  return r;
}

// fast gelu (tanh form)
__device__ __forceinline__ float gelu_f(float x) {
  float t = 0.7978845608028654f * x * (1.0f + 0.044715f * x * x);
  float u = fminf(t * 2.8853900817779268f, 126.0f);
  float e, r;
  asm("v_exp_f32 %0, %1" : "=v"(e) : "v"(u));
  float d = e + 1.0f;
  asm("v_rcp_f32 %0, %1" : "=v"(r) : "v"(d));
  return x * e * r;
}

// ---------------- flat f32 -> bf16 convert, 32 elems/thread, 8-deep load ILP ----------------
__device__ __forceinline__ void cvt32(const float* __restrict__ s, unsigned short* __restrict__ d,
                                      int i) {
  size_t j = (size_t)i * 32;
  float4 v[8];
  #pragma unroll
  for (int t = 0; t < 8; ++t) v[t] = reinterpret_cast<const float4*>(s + j)[t];
  #pragma unroll
  for (int t = 0; t < 4; ++t) {
    u32x4 pv;
    pv.x = pkbf(v[2 * t].x, v[2 * t].y);
    pv.y = pkbf(v[2 * t].z, v[2 * t].w);
    pv.z = pkbf(v[2 * t + 1].x, v[2 * t + 1].y);
    pv.w = pkbf(v[2 * t + 1].z, v[2 * t + 1].w);
    reinterpret_cast<u32x4*>(d + j)[t] = pv;
  }
}

__global__ void cvt_flat(const float* __restrict__ s, unsigned short* __restrict__ d, int n32) {
  int i = blockIdx.x * blockDim.x + threadIdx.x;
  if (i >= n32) return;
  cvt32(s, d, i);
}

// six flat pieces, dispatched piece-major (blockIdx.y) so resident blocks stream one region
__global__ void cvt_multi(const float* s0, const float* s1, const float* s2,
                          const float* s3, const float* s4, const float* s5,
                          unsigned short* d0, unsigned short* d1, unsigned short* d2,
                          unsigned short* d3, unsigned short* d4, unsigned short* d5,
                          int n0, int n1, int n2, int n3, int n4, int n5) {
  const float* s; unsigned short* d; int n32;
  switch (blockIdx.y) {
    case 0: s = s0; d = d0; n32 = n0; break;
    case 1: s = s1; d = d1; n32 = n1; break;
    case 2: s = s2; d = d2; n32 = n2; break;
    case 3: s = s3; d = d3; n32 = n3; break;
    case 4: s = s4; d = d4; n32 = n4; break;
    default: s = s5; d = d5; n32 = n5; break;
  }
  int i = blockIdx.x * blockDim.x + threadIdx.x;
  if (i >= n32) return;
  cvt32(s, d, i);
}

// ---------------- LayerNorm ----------------
__global__ __launch_bounds__(256) void ln_kernel(const float* __restrict__ x,
                                                 const float* __restrict__ g,
                                                 const float* __restrict__ b,
                                                 unsigned short* __restrict__ out) {
  int wave = threadIdx.x >> 6;
  int lane = threadIdx.x & 63;
  int row = blockIdx.x * 4 + wave;
  const float* xr = x + (size_t)row * DM;
  float v[12];
  #pragma unroll
  for (int c = 0; c < 3; ++c) {
    float4 t = *reinterpret_cast<const float4*>(xr + lane * 12 + c * 4);
    v[c * 4 + 0] = t.x; v[c * 4 + 1] = t.y; v[c * 4 + 2] = t.z; v[c * 4 + 3] = t.w;
  }
  float s = 0.f, s2 = 0.f;
  #pragma unroll
  for (int c = 0; c < 12; ++c) { s += v[c]; s2 += v[c] * v[c]; }
  #pragma unroll
  for (int m = 1; m < 64; m <<= 1) { s += __shfl_xor(s, m); s2 += __shfl_xor(s2, m); }
  float mu = s * (1.f / 768.f);
  float var = s2 * (1.f / 768.f) - mu * mu;
  float rstd = rsqrtf(var + 1e-5f);
  unsigned short o[12];
  #pragma unroll
  for (int c = 0; c < 12; ++c) {
    int col = lane * 12 + c;
    o[c] = f2bf((v[c] - mu) * rstd * g[col] + b[col]);
  }
  unsigned short* orow = out + (size_t)row * DM + lane * 12;
  #pragma unroll
  for (int c = 0; c < 3; ++c)
    reinterpret_cast<ushort4*>(orow)[c] = make_ushort4(o[c * 4], o[c * 4 + 1], o[c * 4 + 2], o[c * 4 + 3]);
}

// ---------------- fused: x += pk0+pk1+bias; out = last ? bf16(x) : bf16(LN(x)) ----------------
__global__ __launch_bounds__(256) void ff2_ln(const float* __restrict__ pk,
                                              const float* __restrict__ bias,
                                              float* __restrict__ x,
                                              const float* __restrict__ g,
                                              const float* __restrict__ b,
                                              unsigned short* __restrict__ out,
                                              int last) {
  int wave = threadIdx.x >> 6;
  int lane = threadIdx.x & 63;
  int row = blockIdx.x * 4 + wave;
  size_t base = (size_t)row * DM;
  float v[12];
  #pragma unroll
  for (int c = 0; c < 3; ++c) {
    int col = lane * 12 + c * 4;
    float4 xv = *reinterpret_cast<const float4*>(x + base + col);
    float4 p0 = *reinterpret_cast<const float4*>(pk + base + col);
    float4 p1 = *reinterpret_cast<const float4*>(pk + (size_t)MTOK * DM + base + col);
    float4 bb = *reinterpret_cast<const float4*>(bias + col);
    v[c * 4 + 0] = xv.x + p0.x + p1.x + bb.x;
    v[c * 4 + 1] = xv.y + p0.y + p1.y + bb.y;
    v[c * 4 + 2] = xv.z + p0.z + p1.z + bb.z;
    v[c * 4 + 3] = xv.w + p0.w + p1.w + bb.w;
  }
  #pragma unroll
  for (int c = 0; c < 3; ++c) {
    float4 o = {v[c * 4], v[c * 4 + 1], v[c * 4 + 2], v[c * 4 + 3]};
    *reinterpret_cast<float4*>(x + base + lane * 12 + c * 4) = o;
  }
  unsigned short o[12];
  if (last) {
    #pragma unroll
    for (int c = 0; c < 12; ++c) o[c] = f2bf(v[c]);
  } else {
    float s = 0.f, s2 = 0.f;
    #pragma unroll
    for (int c = 0; c < 12; ++c) { s += v[c]; s2 += v[c] * v[c]; }
    #pragma unroll
    for (int m = 1; m < 64; m <<= 1) { s += __shfl_xor(s, m); s2 += __shfl_xor(s2, m); }
    float mu = s * (1.f / 768.f);
    float var = s2 * (1.f / 768.f) - mu * mu;
    float rstd = rsqrtf(var + 1e-5f);
    #pragma unroll
    for (int c = 0; c < 12; ++c) {
      int col = lane * 12 + c;
      o[c] = f2bf((v[c] - mu) * rstd * g[col] + b[col]);
    }
  }
  unsigned short* orow = out + base + lane * 12;
  #pragma unroll
  for (int c = 0; c < 3; ++c)
    reinterpret_cast<ushort4*>(orow)[c] = make_ushort4(o[c * 4], o[c * 4 + 1], o[c * 4 + 2], o[c * 4 + 3]);
}

// ---------------- GEMM: C[M,N] = A[M,K] @ B[N,K]^T (bf16 LDS, gload_lds both operands) ----------------
// SEG3: B/bias selected per 768-row segment (fused QKV). EPI as before.
template<int BM, int BN, int EPI, bool SEG3>
__global__ __launch_bounds__(256) void gemm_bt(const unsigned short* __restrict__ A,
                                               const unsigned short* __restrict__ B0,
                                               const unsigned short* __restrict__ B1,
                                               const unsigned short* __restrict__ B2,
                                               const float* __restrict__ bias0,
                                               const float* __restrict__ bias1,
                                               const float* __restrict__ bias2,
                                               const float* __restrict__ resid,
                                               float* __restrict__ outf,
                                               unsigned short* __restrict__ outb,
                                               int M, int N, int K) {
  constexpr int MI = BM / 32;
  constexpr int NI = BN / 32;
  constexpr int ACH = BM / 32;
  constexpr int BCH = BN / 32;
  __shared__ unsigned short As[2][BM * 64];
  __shared__ unsigned short Bs[2][BN * 64];
  const int tid = threadIdx.x;
  const int w = tid >> 6, lane = tid & 63;
  const int wr = w >> 1, wc = w & 1;
  const int l15 = lane & 15, rq = lane >> 4;
  const int bM = blockIdx.y * BM, bNg = blockIdx.x * BN;
  const unsigned short* Bp; const float* biasp; int bN;
  if constexpr (SEG3) {
    int seg = bNg / 768;
    Bp    = (seg == 0) ? B0 : ((seg == 1) ? B1 : B2);
    biasp = (seg == 0) ? bias0 : ((seg == 1) ? bias1 : bias2);
    bN = bNg - seg * 768;
  } else {
    Bp = B0; biasp = bias0; bN = bNg;
  }
  const f32x4 zero4 = {0.f, 0.f, 0.f, 0.f};
  f32x4 acc[MI][NI];
  #pragma unroll
  for (int mi = 0; mi < MI; ++mi)
    #pragma unroll
    for (int ni = 0; ni < NI; ++ni) acc[mi][ni] = zero4;
  const int srow = lane >> 3;
  const int scol = ((lane & 7) ^ (lane >> 3)) * 8;
  auto stage = [&](int bf, int k0) {
    #pragma unroll
    for (int cc = 0; cc < ACH; ++cc) {
      int c = w * ACH + cc;
      gload16(A + (size_t)(bM + 8 * c + srow) * K + k0 + scol, (void*)(&As[bf][c * 512]));
    }
    #pragma unroll
    for (int cc = 0; cc < BCH; ++cc) {
      int c = w * BCH + cc;
      gload16(Bp + (size_t)(bN + 8 * c + srow) * K + k0 + scol, (void*)(&Bs[bf][c * 512]));
    }
  };
  const int kper = K / gridDim.z;
  const int kbase = blockIdx.z * kper;
  const int nt = kper / 64;
  stage(0, kbase);
  __syncthreads();
  int buf = 0;
  for (int t = 0; t < nt; ++t) {
    if (t + 1 < nt) stage(buf ^ 1, kbase + (t + 1) * 64);
    #pragma unroll
    for (int kk = 0; kk < 2; ++kk) {
      bf16x8 af[MI], bfr[NI];
      #pragma unroll
      for (int mi = 0; mi < MI; ++mi) {
        int row = wr * (BM / 2) + mi * 16 + l15;
        af[mi] = *(const bf16x8*)(&As[buf][row * 64 + (((kk * 4 + rq) ^ (row & 7)) * 8)]);
      }
      #pragma unroll
      for (int ni = 0; ni < NI; ++ni) {
        int row = wc * (BN / 2) + ni * 16 + l15;
        bfr[ni] = *(const bf16x8*)(&Bs[buf][row * 64 + (((kk * 4 + rq) ^ (row & 7)) * 8)]);
      }
      #pragma unroll
      for (int mi = 0; mi < MI; ++mi)
        #pragma unroll
        for (int ni = 0; ni < NI; ++ni)
          acc[mi][ni] = MFMA(af[mi], bfr[ni], acc[mi][ni]);
    }
    __syncthreads();
    buf ^= 1;
  }
  #pragma unroll
  for (int mi = 0; mi < MI; ++mi)
    #pragma unroll
    for (int ni = 0; ni < NI; ++ni)
      #pragma unroll
      for (int r = 0; r < 4; ++r) {
        int row = bM + wr * (BM / 2) + mi * 16 + 4 * rq + r;
        int colL = bN + wc * (BN / 2) + ni * 16 + l15;
        int colG = bNg + wc * (BN / 2) + ni * 16 + l15;
        if constexpr (EPI == 4) {
          outf[(size_t)blockIdx.z * M * N + (size_t)row * N + colG] = acc[mi][ni][r];
        } else {
          float val = acc[mi][ni][r] + biasp[colL];
          if constexpr (EPI == 0) {
            outb[(size_t)row * N + colG] = f2bf(val);
          } else if constexpr (EPI == 1) {
            outb[(size_t)row * N + colG] = f2bf(gelu_f(val));
          } else if constexpr (EPI == 2) {
            outf[(size_t)row * N + colG] = resid[(size_t)row * N + colG] + val;
          } else {
            outf[(size_t)row * N + colG] = val;
          }
        }
      }
}

// ---------------- sigmoid attention (m-split partials) ----------------
__global__ __launch_bounds__(256) void attn_kernel(const unsigned short* __restrict__ qkv,
                                                   float* __restrict__ po,
                                                   float* __restrict__ prs) {
  __shared__ unsigned short Ks[64 * 64];
  __shared__ unsigned short vt[64 * 72];
  __shared__ unsigned short pl[4][16 * 72];
  const int tid = threadIdx.x;
  const int w = tid >> 6, lane = tid & 63;
  const int l15 = lane & 15, rq = lane >> 4;
  const int b = blockIdx.y / NH, h = blockIdx.y % NH;
  const int n0 = blockIdx.x * 64;
  const int part = blockIdx.z;
  const unsigned short* base = qkv + (size_t)(b * NSEQ) * QKVN + h * HD;
  bf16x8 aq0, aq1;
  {
    const unsigned short* qp = base + (size_t)(n0 + w * 16 + l15) * QKVN + rq * 8;
    aq0 = *(const bf16x8*)qp;
    aq1 = *(const bf16x8*)(qp + 32);
  }
  float rs[4] = {0.f, 0.f, 0.f, 0.f};
  const f32x4 zero4 = {0.f, 0.f, 0.f, 0.f};
  f32x4 acco[4];
  #pragma unroll
  for (int j = 0; j < 4; ++j) acco[j] = zero4;
  unsigned short* plw = &pl[w][0];

  for (int mt = 0; mt < 4; ++mt) {
    const int m0 = part * 256 + mt * 64;
    __syncthreads();
    #pragma unroll
    for (int it = 0; it < 2; ++it) {
      int idx = tid + it * 256;
      int r = idx >> 3, c = idx & 7;
      bf16x8 kv = *(const bf16x8*)(base + 768 + (size_t)(m0 + r) * QKVN + c * 8);
      *(bf16x8*)(Ks + r * 64 + (c ^ (r & 7)) * 8) = kv;
      int cd = idx & 63, g = (idx >> 6) & 7;
      const unsigned short* vp = base + 1536 + (size_t)(m0 + g * 8) * QKVN + cd;
      bf16x8 vv;
      #pragma unroll
      for (int j = 0; j < 8; ++j) vv[j] = (short)vp[(size_t)j * QKVN];
      *(bf16x8*)(vt + cd * 72 + g * 8) = vv;
    }
    __syncthreads();
    #pragma unroll
    for (int ni = 0; ni < 4; ++ni) {
      int kr = ni * 16 + l15;
      bf16x8 bk0 = *(const bf16x8*)(Ks + kr * 64 + ((rq) ^ (kr & 7)) * 8);
      bf16x8 bk1 = *(const bf16x8*)(Ks + kr * 64 + ((rq + 4) ^ (kr & 7)) * 8);
      f32x4 z = zero4;
      z = MFMA(aq0, bk0, z);
      z = MFMA(aq1, bk1, z);
      #pragma unroll
      for (int r = 0; r < 4; ++r) {
        float p = sigmoid8(z[r]);
        rs[r] += p;
        plw[(4 * rq + r) * 72 + ni * 16 + l15] = f2bf(p);
      }
    }
    #pragma unroll
    for (int kk = 0; kk < 2; ++kk) {
      bf16x8 ap = *(const bf16x8*)(plw + l15 * 72 + kk * 32 + rq * 8);
      #pragma unroll
      for (int j2 = 0; j2 < 4; ++j2) {
        bf16x8 bvv = *(const bf16x8*)(vt + (j2 * 16 + l15) * 72 + kk * 32 + rq * 8);
        acco[j2] = MFMA(ap, bvv, acco[j2]);
      }
    }
  }
  #pragma unroll
  for (int m = 1; m < 16; m <<= 1)
    #pragma unroll
    for (int r = 0; r < 4; ++r) rs[r] += __shfl_xor(rs[r], m);
  float* pop = po + (size_t)part * MTOK * DM;
  #pragma unroll
  for (int j2 = 0; j2 < 4; ++j2)
    #pragma unroll
    for (int r = 0; r < 4; ++r) {
      int row = b * NSEQ + n0 + w * 16 + 4 * rq + r;
      int col = h * HD + j2 * 16 + l15;
      pop[(size_t)row * DM + col] = acco[j2][r];
    }
  if (l15 == 0) {
    #pragma unroll
    for (int r = 0; r < 4; ++r)
      prs[((size_t)part * (BB * NH) + blockIdx.y) * NSEQ + n0 + w * 16 + 4 * rq + r] = rs[r];
  }
}

// ---------------- combine attention partials -> bf16 ----------------
__global__ __launch_bounds__(256) void attn_combine(const float* __restrict__ po,
                                                    const float* __restrict__ prs,
                                                    unsigned short* __restrict__ attnbf) {
  int i = blockIdx.x * 256 + threadIdx.x;
  int e = i * 4;
  int row = e / DM, col = e % DM;
  int b = row >> 9, n = row & 511, h = col >> 6;
  float r0 = prs[((size_t)(b * NH + h)) * NSEQ + n];
  float r1 = prs[(size_t)(BB * NH) * NSEQ + ((size_t)(b * NH + h)) * NSEQ + n];
  float inv = 1.f / (r0 + r1 + 1e-6f);
  float4 p0 = *reinterpret_cast<const float4*>(po + e);
  float4 p1 = *reinterpret_cast<const float4*>(po + (size_t)MTOK * DM + e);
  ushort4 o;
  o.x = f2bf((p0.x + p1.x) * inv);
  o.y = f2bf((p0.y + p1.y) * inv);
  o.z = f2bf((p0.z + p1.z) * inv);
  o.w = f2bf((p0.w + p1.w) * inv);
  *reinterpret_cast<ushort4*>(attnbf + e) = o;
}

// ---------------- raw_w second projection ----------------
__global__ __launch_bounds__(128) void wr2_kernel(const unsigned short* __restrict__ h1,
                                                  const float* __restrict__ wr2,
                                                  const float* __restrict__ br2,
                                                  float* __restrict__ raww) {
  __shared__ float hrow[DR1];
  int row = blockIdx.x;
  const unsigned short* hp = h1 + (size_t)row * DR1;
  for (int c = threadIdx.x; c < DR1; c += 128) hrow[c] = bf2f(hp[c]);
  __syncthreads();
  int j = threadIdx.x;
  if (j < TH) {
    const float* wrow = wr2 + (size_t)j * DR1;
    float acc = 0.f;
    for (int c4 = 0; c4 < DR1 / 4; ++c4) {
      float4 hv = *reinterpret_cast<const float4*>(hrow + c4 * 4);
      float4 wv = *reinterpret_cast<const float4*>(wrow + c4 * 4);
      acc += hv.x * wv.x + hv.y * wv.y + hv.z * wv.z + hv.w * wv.w;
    }
    raww[(size_t)row * TH + j] = acc + br2[j];
  }
}

// ---------------- aggregation partials ----------------
__global__ __launch_bounds__(256) void agg_kernel(const unsigned short* __restrict__ qkv_all,
                                                  const float* __restrict__ raww,
                                                  float* __restrict__ part) {
  __shared__ unsigned short Ks[64 * 64];
  __shared__ unsigned short Qs[64 * 64];
  const int tid = threadIdx.x;
  const int w = tid >> 6, lane = tid & 63;
  const int l15 = lane & 15, rq = lane >> 4;
  const int z = blockIdx.z;
  const int l = z >> 2, b = z & 3;
  const int m0 = blockIdx.x * 64, nb = blockIdx.y * 64;
  const unsigned short* base = qkv_all + (size_t)l * MTOK * QKVN + (size_t)(b * NSEQ) * QKVN;
  const f32x4 zero4 = {0.f, 0.f, 0.f, 0.f};
  float acc[4][4];
  #pragma unroll
  for (int ni = 0; ni < 4; ++ni)
    #pragma unroll
    for (int r = 0; r < 4; ++r) acc[ni][r] = 0.f;
  for (int h = 0; h < NH; ++h) {
    __syncthreads();
    #pragma unroll
    for (int it = 0; it < 2; ++it) {
      int idx = tid + it * 256;
      int r = idx >> 3, c = idx & 7;
      bf16x8 kv = *(const bf16x8*)(base + (size_t)(m0 + r) * QKVN + 768 + h * HD + c * 8);
      *(bf16x8*)(Ks + r * 64 + (c ^ (r & 7)) * 8) = kv;
      bf16x8 qv = *(const bf16x8*)(base + (size_t)(nb + r) * QKVN + h * HD + c * 8);
      *(bf16x8*)(Qs + r * 64 + (c ^ (r & 7)) * 8) = qv;
    }
    __syncthreads();
    const int qr = w * 16 + l15;
    bf16x8 aq0 = *(const bf16x8*)(Qs + qr * 64 + ((rq) ^ (qr & 7)) * 8);
    bf16x8 aq1 = *(const bf16x8*)(Qs + qr * 64 + ((rq + 4) ^ (qr & 7)) * 8);
    float wl[4];
    #pragma unroll
    for (int r = 0; r < 4; ++r)
      wl[r] = raww[(size_t)(b * NSEQ + nb + w * 16 + 4 * rq + r) * TH + l * NH + h];
    #pragma unroll
    for (int ni = 0; ni < 4; ++ni) {
      int kr = ni * 16 + l15;
      bf16x8 bk0 = *(const bf16x8*)(Ks + kr * 64 + ((rq) ^ (kr & 7)) * 8);
      bf16x8 bk1 = *(const bf16x8*)(Ks + kr * 64 + ((rq + 4) ^ (kr & 7)) * 8);
      f32x4 zz = zero4;
      zz = MFMA(aq0, bk0, zz);
      zz = MFMA(aq1, bk1, zz);
      #pragma unroll
      for (int r = 0; r < 4; ++r) {
        acc[ni][r] += wl[r] * sigmoid8(zz[r]);
      }
    }
  }
  #pragma unroll
  for (int ni = 0; ni < 4; ++ni)
    #pragma unroll
    for (int r = 0; r < 4; ++r) {
      int n = nb + w * 16 + 4 * rq + r;
      part[((size_t)z * NSEQ + n) * NSEQ + m0 + ni * 16 + l15] = acc[ni][r];
    }
}

// ---------------- reduce partials over layers + bias + diag mask ----------------
__global__ __launch_bounds__(256) void agg_reduce(const float* __restrict__ part,
                                                  const float* __restrict__ agg_bias,
                                                  float* __restrict__ out) {
  int i = blockIdx.x * 256 + threadIdx.x;
  int e = i * 4;
  float4 s = {0.f, 0.f, 0.f, 0.f};
  #pragma unroll
  for (int l = 0; l < LAYERS; ++l) {
    float4 p = *reinterpret_cast<const float4*>(part + (size_t)l * BB * NSEQ * NSEQ + e);
    s.x += p.x; s.y += p.y; s.z += p.z; s.w += p.w;
  }
  int n = (e >> 9) & 511, m = e & 511;
  float ab = agg_bias[0];
  float4 o;
  o.x = (n == m)     ? ab : s.x + ab;
  o.y = (n == m + 1) ? ab : s.y + ab;
  o.z = (n == m + 2) ? ab : s.z + ab;
  o.w = (n == m + 3) ? ab : s.w + ab;
  *reinterpret_cast<float4*>(out + e) = o;
}

// ---------------- host ----------------
extern "C" void kernel_launch(void* const* d_in, const int* in_sizes, int n_in,
                              void* d_out, int out_size, void* d_ws, size_t ws_size,
                              hipStream_t stream) {
  const float* emb  = (const float*)d_in[0];
  const float* Win  = (const float*)d_in[1];
  const float* b_in = (const float*)d_in[2];
  const float* Wq   = (const float*)d_in[3];
  const float* bq   = (const float*)d_in[4];
  const float* Wk   = (const float*)d_in[5];
  const float* bk   = (const float*)d_in[6];
  const float* Wv   = (const float*)d_in[7];
  const float* bv   = (const float*)d_in[8];
  const float* Wo   = (const float*)d_in[9];
  const float* bo   = (const float*)d_in[10];
  const float* g1   = (const float*)d_in[11];
  const float* be1  = (const float*)d_in[12];
  const float* g2   = (const float*)d_in[13];
  const float* be2  = (const float*)d_in[14];
  const float* W1   = (const float*)d_in[15];
  const float* bf1  = (const float*)d_in[16];
  const float* W2   = (const float*)d_in[17];
  const float* bf2  = (const float*)d_in[18];
  const float* Wr1  = (const float*)d_in[19];
  const float* br1  = (const float*)d_in[20];
  const float* Wr2  = (const float*)d_in[21];
  const float* br2  = (const float*)d_in[22];
  const float* aggb = (const float*)d_in[23];
  float* out = (float*)d_out;
  (void)in_sizes; (void)n_in; (void)out_size; (void)ws_size;

  char* ws = (char*)d_ws;
  size_t off = 0;
  auto alloc = [&](size_t bytes) -> char* {
    char* p = ws + off;
    off += (bytes + 255) & ~(size_t)255;
    return p;
  };
  // persistent region (all-layer weights, flat layouts mirroring the inputs)
  unsigned short* qw6    = (unsigned short*)alloc((size_t)LAYERS * DM * DM * 2);
  unsigned short* kw6    = (unsigned short*)alloc((size_t)LAYERS * DM * DM * 2);
  unsigned short* vw6    = (unsigned short*)alloc((size_t)LAYERS * DM * DM * 2);
  unsigned short* wow6   = (unsigned short*)alloc((size_t)LAYERS * DM * DM * 2);
  unsigned short* w1w6   = (unsigned short*)alloc((size_t)LAYERS * DFF * DM * 2);
  unsigned short* w2w6   = (unsigned short*)alloc((size_t)LAYERS * DM * DFF * 2);
  unsigned short* winw   = (unsigned short*)alloc((size_t)DM * DM * 2);
  unsigned short* wr1w   = (unsigned short*)alloc((size_t)DR1 * DM * 2);
  unsigned short* h1bf   = (unsigned short*)alloc((size_t)MTOK * DR1 * 2);
  float*          raww   = (float*)alloc((size_t)MTOK * TH * 4);
  float*          prs    = (float*)alloc((size_t)2 * BB * NH * NSEQ * 4);
  float*          skbuf  = (float*)alloc((size_t)2 * MTOK * DM * 4);
  unsigned short* qkvall = (unsigned short*)alloc((size_t)LAYERS * MTOK * QKVN * 2);
  // scratch region
  char* scratch = alloc(0);
  unsigned short* embbf  = (unsigned short*)(scratch);
  float*          x      = (float*)(scratch + 3145728);
  unsigned short* nbf    = (unsigned short*)(scratch + 3145728 + 6291456);
  unsigned short* attnbf = (unsigned short*)(scratch + 3145728 + 6291456 + 3145728);
  char*           S      = scratch + 3145728 + 6291456 + 3145728 + 3145728;
  unsigned short* xbf    = (unsigned short*)(S + 12582912);
  float*          po     = (float*)S;
  unsigned short* ff1bf  = (unsigned short*)S;
  float*          part   = (float*)scratch;   // 25.2 MB, aliases dead early scratch

  // converts: pure flat streams. piece-major dispatch (blockIdx.y outer).
  const int NQKVO = (LAYERS * DM * DM) / 32;   // 110592 -> 432 blocks
  const int NWIN  = (DM * DM) / 32;            // 18432  -> 72
  const int NWR1  = (DR1 * DM) / 32;           // 9216   -> 36
  cvt_multi<<<dim3(432, 6), 256, 0, stream>>>(Wq, Wk, Wv, Wo, Win, Wr1,
                                              qw6, kw6, vw6, wow6, winw, wr1w,
                                              NQKVO, NQKVO, NQKVO, NQKVO, NWIN, NWR1);
  cvt_flat<<<1728, 256, 0, stream>>>(W1, w1w6, (LAYERS * DFF * DM) / 32);
  cvt_flat<<<1728, 256, 0, stream>>>(W2, w2w6, (LAYERS * DM * DFF) / 32);
  cvt_flat<<<192, 256, 0, stream>>>(emb, embbf, (MTOK * DM) / 32);

  dim3 g768(DM / 64, MTOK / 64);        // (12,32)
  gemm_bt<64, 64, 3, false><<<g768, 256, 0, stream>>>(embbf, winw, winw, winw,
                                                      b_in, b_in, b_in,
                                                      nullptr, x, nullptr, MTOK, DM, DM);
  ln_kernel<<<512, 256, 0, stream>>>(x, g1, be1, nbf);   // layer-0 LN1

  for (int l = 0; l < LAYERS; ++l) {
    unsigned short* qkvl = qkvall + (size_t)l * MTOK * QKVN;
    dim3 gqkv(QKVN / 128, MTOK / 64);   // (18,32) BM=64,BN=128
    gemm_bt<64, 128, 0, true><<<gqkv, 256, 0, stream>>>(nbf,
                                                        qw6 + (size_t)l * DM * DM,
                                                        kw6 + (size_t)l * DM * DM,
                                                        vw6 + (size_t)l * DM * DM,
                                                        bq + l * DM, bk + l * DM, bv + l * DM,
                                                        nullptr, nullptr, qkvl, MTOK, QKVN, DM);
    attn_kernel<<<dim3(8, BB * NH, 2), 256, 0, stream>>>(qkvl, po, prs);
    attn_combine<<<(MTOK * DM / 4) / 256, 256, 0, stream>>>(po, prs, attnbf);
    const unsigned short* wo = wow6 + (size_t)l * DM * DM;
    gemm_bt<64, 64, 2, false><<<g768, 256, 0, stream>>>(attnbf, wo, wo, wo,
                                                        bo + l * DM, nullptr, nullptr,
                                                        x, x, nullptr, MTOK, DM, DM);
    ln_kernel<<<512, 256, 0, stream>>>(x, g2 + l * DM, be2 + l * DM, nbf);
    const unsigned short* w1 = w1w6 + (size_t)l * DFF * DM;
    dim3 gff1(DFF / 128, MTOK / 64);    // (24,32) BM=64,BN=128
    gemm_bt<64, 128, 1, false><<<gff1, 256, 0, stream>>>(nbf, w1, w1, w1,
                                                         bf1 + l * DFF, nullptr, nullptr,
                                                         nullptr, nullptr, ff1bf, MTOK, DFF, DM);
    const unsigned short* w2 = w2w6 + (size_t)l * DM * DFF;
    dim3 gff2(DM / 64, MTOK / 64, 2);   // (12,32,2) split-K
    gemm_bt<64, 64, 4, false><<<gff2, 256, 0, stream>>>(ff1bf, w2, w2, w2,
                                                        nullptr, nullptr, nullptr,
                                                        nullptr, skbuf, nullptr, MTOK, DM, DFF);
    if (l < LAYERS - 1) {
      ff2_ln<<<512, 256, 0, stream>>>(skbuf, bf2 + l * DM, x,
                                      g1 + (l + 1) * DM, be1 + (l + 1) * DM, nbf, 0);
    } else {
      ff2_ln<<<512, 256, 0, stream>>>(skbuf, bf2 + l * DM, x, g1, be1, xbf, 1);
    }
  }

  dim3 gr1(DR1 / 64, MTOK / 64);        // (6,32)
  gemm_bt<64, 64, 1, false><<<gr1, 256, 0, stream>>>(xbf, wr1w, wr1w, wr1w,
                                                     br1, br1, br1,
                                                     nullptr, nullptr, h1bf, MTOK, DR1, DM);
  wr2_kernel<<<MTOK, 128, 0, stream>>>(h1bf, Wr2, br2, raww);
  agg_kernel<<<dim3(8, 8, LAYERS * BB), 256, 0, stream>>>(qkvall, raww, part);
  agg_reduce<<<(BB * NSEQ * NSEQ / 4) / 256, 256, 0, stream>>>(part, aggb, out);
}

// Round 10
// 690.814 us; speedup vs baseline: 1.0589x; 1.0589x over previous
//
#include <hip/hip_runtime.h>
#include <stdint.h>

#define LAYERS 6
#define BB 4
#define NSEQ 512
#define DM 768
#define NH 12
#define HD 64
#define DFF 3072
#define MTOK 2048   // B*N
#define QKVN 2304
#define DR1 384
#define TH 72

typedef __attribute__((ext_vector_type(8))) short bf16x8;
typedef __attribute__((ext_vector_type(4))) float f32x4;
typedef __attribute__((ext_vector_type(4))) unsigned int u32x4;

__device__ __forceinline__ unsigned short f2bf(float f) {
  union { float f; uint32_t u; } v; v.f = f;
  return (unsigned short)((v.u + 0x7fffu + ((v.u >> 16) & 1u)) >> 16);
}
__device__ __forceinline__ float bf2f(unsigned short h) {
  union { uint32_t u; float f; } v; v.u = ((uint32_t)h) << 16;
  return v.f;
}
// pack two f32 -> two bf16 (RNE) in one instruction
__device__ __forceinline__ uint32_t pkbf(float lo, float hi) {
  uint32_t r;
  asm("v_cvt_pk_bf16_f32 %0, %1, %2" : "=v"(r) : "v"(lo), "v"(hi));
  return r;
}
__device__ __forceinline__ void gload16(const void* g, void* l) {
  __builtin_amdgcn_global_load_lds((const __attribute__((address_space(1))) void*)g,
                                   (__attribute__((address_space(3))) void*)l, 16, 0, 0);
}
#define MFMA(a, b, c) __builtin_amdgcn_mfma_f32_16x16x32_bf16(a, b, c, 0, 0, 0)

// fast sigmoid(s * 0.125)
__device__ __forceinline__ float sigmoid8(float s) {
  float e, r;
  float t = s * -0.18033688011112443f;
  asm("v_exp_f32 %0, %1" : "=v"(e) : "v"(t));
  float d = 1.0f + e;
  asm("v_rcp_f32 %0, %1" : "=v"(r) : "v"(d));
  return r;
}

// fast gelu (tanh form)
__device__ __forceinline__ float gelu_f(float x) {
  float t = 0.7978845608028654f * x * (1.0f + 0.044715f * x * x);
  float u = fminf(t * 2.8853900817779268f, 126.0f);
  float e, r;
  asm("v_exp_f32 %0, %1" : "=v"(e) : "v"(u));
  float d = e + 1.0f;
  asm("v_rcp_f32 %0, %1" : "=v"(r) : "v"(d));
  return x * e * r;
}

// ---------------- 8-elem f32 -> bf16 convert helper ----------------
__device__ __forceinline__ void cvt8(const float* __restrict__ s8, unsigned short* __restrict__ dst) {
  float4 v0 = *reinterpret_cast<const float4*>(s8);
  float4 v1 = *reinterpret_cast<const float4*>(s8 + 4);
  u32x4 pv;
  pv.x = pkbf(v0.x, v0.y);
  pv.y = pkbf(v0.z, v0.w);
  pv.z = pkbf(v1.x, v1.y);
  pv.w = pkbf(v1.z, v1.w);
  *reinterpret_cast<u32x4*>(dst) = pv;
}

// ---------------- ALL weight/input converts in ONE dispatch ----------------
// blockIdx.y = layer for the per-layer pieces (QKV interleaved, Wo, W1, W2 + bias concat).
// Blocks with i >= per-layer range handle the shared pieces: y=0 -> emb, y=1 -> Win, y=2 -> Wr1.
__global__ void convert_all(const float* __restrict__ Wq, const float* __restrict__ Wk,
                            const float* __restrict__ Wv, const float* __restrict__ Wo,
                            const float* __restrict__ W1, const float* __restrict__ W2,
                            const float* __restrict__ bqA, const float* __restrict__ bkA,
                            const float* __restrict__ bvA,
                            const float* __restrict__ emb, const float* __restrict__ Win,
                            const float* __restrict__ Wr1,
                            unsigned short* __restrict__ qkvw6, float* __restrict__ qkvb6,
                            unsigned short* __restrict__ wow6, unsigned short* __restrict__ w1w6,
                            unsigned short* __restrict__ w2w6,
                            unsigned short* __restrict__ embbf, unsigned short* __restrict__ winw,
                            unsigned short* __restrict__ wr1w) {
  const int A8 = (QKVN * DM) / 8;   // 221184
  const int B8 = (DM * DM) / 8;     // 73728
  const int C8 = (DFF * DM) / 8;    // 294912
  const int MAIN = A8 + B8 + 2 * C8;  // 884736 (= 3456 blocks)
  int i = blockIdx.x * blockDim.x + threadIdx.x;
  const int l = blockIdx.y;
  if (i >= MAIN) {
    // shared pieces
    int j = i - MAIN;
    const float* s; unsigned short* d; int n8;
    if (l == 0)      { s = emb; d = embbf; n8 = (MTOK * DM) / 8; }
    else if (l == 1) { s = Win; d = winw;  n8 = (DM * DM) / 8; }
    else if (l == 2) { s = Wr1; d = wr1w;  n8 = (DR1 * DM) / 8; }
    else return;
    if (j >= n8) return;
    cvt8(s + (size_t)j * 8, d + (size_t)j * 8);
    return;
  }
  const float* wq = Wq + (size_t)l * DM * DM;
  const float* wk = Wk + (size_t)l * DM * DM;
  const float* wv = Wv + (size_t)l * DM * DM;
  const float* wo = Wo + (size_t)l * DM * DM;
  const float* w1 = W1 + (size_t)l * DFF * DM;
  const float* w2 = W2 + (size_t)l * DM * DFF;
  unsigned short* qkvw = qkvw6 + (size_t)l * QKVN * DM;
  unsigned short* wow  = wow6  + (size_t)l * DM * DM;
  unsigned short* w1w  = w1w6  + (size_t)l * DFF * DM;
  unsigned short* w2w  = w2w6  + (size_t)l * DM * DFF;
  float* qkvb = qkvb6 + (size_t)l * QKVN;
  if (i < QKVN / 8) {   // bias concat (8 entries never straddle a 768-boundary)
    int j = i * 8;
    int seg = j / DM, c = j % DM;
    const float* src = (seg == 0) ? (bqA + l * DM) : ((seg == 1) ? (bkA + l * DM) : (bvA + l * DM));
    *reinterpret_cast<float4*>(qkvb + j)     = *reinterpret_cast<const float4*>(src + c);
    *reinterpret_cast<float4*>(qkvb + j + 4) = *reinterpret_cast<const float4*>(src + c + 4);
  }
  const float* s8; unsigned short* dst;
  if (i < A8) {
    int j = i * 8; int row = j / DM; int c = j % DM;
    const float* w = (row < DM) ? wq : ((row < 2 * DM) ? wk : wv);
    s8 = w + (size_t)(row % DM) * DM + c; dst = qkvw + j;
  } else if (i < A8 + B8) {
    int j = (i - A8) * 8; s8 = wo + j; dst = wow + j;
  } else if (i < A8 + B8 + C8) {
    int j = (i - A8 - B8) * 8; s8 = w1 + j; dst = w1w + j;
  } else {
    int j = (i - A8 - B8 - C8) * 8; s8 = w2 + j; dst = w2w + j;
  }
  cvt8(s8, dst);
}

// ---------------- LayerNorm ----------------
__global__ __launch_bounds__(256) void ln_kernel(const float* __restrict__ x,
                                                 const float* __restrict__ g,
                                                 const float* __restrict__ b,
                                                 unsigned short* __restrict__ out) {
  int wave = threadIdx.x >> 6;
  int lane = threadIdx.x & 63;
  int row = blockIdx.x * 4 + wave;
  const float* xr = x + (size_t)row * DM;
  float v[12];
  #pragma unroll
  for (int c = 0; c < 3; ++c) {
    float4 t = *reinterpret_cast<const float4*>(xr + lane * 12 + c * 4);
    v[c * 4 + 0] = t.x; v[c * 4 + 1] = t.y; v[c * 4 + 2] = t.z; v[c * 4 + 3] = t.w;
  }
  float s = 0.f, s2 = 0.f;
  #pragma unroll
  for (int c = 0; c < 12; ++c) { s += v[c]; s2 += v[c] * v[c]; }
  #pragma unroll
  for (int m = 1; m < 64; m <<= 1) { s += __shfl_xor(s, m); s2 += __shfl_xor(s2, m); }
  float mu = s * (1.f / 768.f);
  float var = s2 * (1.f / 768.f) - mu * mu;
  float rstd = rsqrtf(var + 1e-5f);
  unsigned short o[12];
  #pragma unroll
  for (int c = 0; c < 12; ++c) {
    int col = lane * 12 + c;
    o[c] = f2bf((v[c] - mu) * rstd * g[col] + b[col]);
  }
  unsigned short* orow = out + (size_t)row * DM + lane * 12;
  #pragma unroll
  for (int c = 0; c < 3; ++c)
    reinterpret_cast<ushort4*>(orow)[c] = make_ushort4(o[c * 4], o[c * 4 + 1], o[c * 4 + 2], o[c * 4 + 3]);
}

// ---------------- fused: x += pk0+pk1+bias; out = last ? bf16(x) : bf16(LN(x)) ----------------
__global__ __launch_bounds__(256) void ff2_ln(const float* __restrict__ pk,
                                              const float* __restrict__ bias,
                                              float* __restrict__ x,
                                              const float* __restrict__ g,
                                              const float* __restrict__ b,
                                              unsigned short* __restrict__ out,
                                              int last) {
  int wave = threadIdx.x >> 6;
  int lane = threadIdx.x & 63;
  int row = blockIdx.x * 4 + wave;
  size_t base = (size_t)row * DM;
  float v[12];
  #pragma unroll
  for (int c = 0; c < 3; ++c) {
    int col = lane * 12 + c * 4;
    float4 xv = *reinterpret_cast<const float4*>(x + base + col);
    float4 p0 = *reinterpret_cast<const float4*>(pk + base + col);
    float4 p1 = *reinterpret_cast<const float4*>(pk + (size_t)MTOK * DM + base + col);
    float4 bb = *reinterpret_cast<const float4*>(bias + col);
    v[c * 4 + 0] = xv.x + p0.x + p1.x + bb.x;
    v[c * 4 + 1] = xv.y + p0.y + p1.y + bb.y;
    v[c * 4 + 2] = xv.z + p0.z + p1.z + bb.z;
    v[c * 4 + 3] = xv.w + p0.w + p1.w + bb.w;
  }
  #pragma unroll
  for (int c = 0; c < 3; ++c) {
    float4 o = {v[c * 4], v[c * 4 + 1], v[c * 4 + 2], v[c * 4 + 3]};
    *reinterpret_cast<float4*>(x + base + lane * 12 + c * 4) = o;
  }
  unsigned short o[12];
  if (last) {
    #pragma unroll
    for (int c = 0; c < 12; ++c) o[c] = f2bf(v[c]);
  } else {
    float s = 0.f, s2 = 0.f;
    #pragma unroll
    for (int c = 0; c < 12; ++c) { s += v[c]; s2 += v[c] * v[c]; }
    #pragma unroll
    for (int m = 1; m < 64; m <<= 1) { s += __shfl_xor(s, m); s2 += __shfl_xor(s2, m); }
    float mu = s * (1.f / 768.f);
    float var = s2 * (1.f / 768.f) - mu * mu;
    float rstd = rsqrtf(var + 1e-5f);
    #pragma unroll
    for (int c = 0; c < 12; ++c) {
      int col = lane * 12 + c;
      o[c] = f2bf((v[c] - mu) * rstd * g[col] + b[col]);
    }
  }
  unsigned short* orow = out + base + lane * 12;
  #pragma unroll
  for (int c = 0; c < 3; ++c)
    reinterpret_cast<ushort4*>(orow)[c] = make_ushort4(o[c * 4], o[c * 4 + 1], o[c * 4 + 2], o[c * 4 + 3]);
}

// ---------------- GEMM: C[M,N] = A[M,K] @ B[N,K]^T (bf16 LDS, gload_lds both operands) ----------------
template<int BM, int BN, int EPI>
__global__ __launch_bounds__(256) void gemm_bt(const unsigned short* __restrict__ A,
                                               const unsigned short* __restrict__ B,
                                               const float* __restrict__ bias,
                                               const float* __restrict__ resid,
                                               float* __restrict__ outf,
                                               unsigned short* __restrict__ outb,
                                               int M, int N, int K) {
  constexpr int MI = BM / 32;
  constexpr int NI = BN / 32;
  constexpr int ACH = BM / 32;
  constexpr int BCH = BN / 32;
  __shared__ unsigned short As[2][BM * 64];
  __shared__ unsigned short Bs[2][BN * 64];
  const int tid = threadIdx.x;
  const int w = tid >> 6, lane = tid & 63;
  const int wr = w >> 1, wc = w & 1;
  const int l15 = lane & 15, rq = lane >> 4;
  const int bM = blockIdx.y * BM, bN = blockIdx.x * BN;
  const f32x4 zero4 = {0.f, 0.f, 0.f, 0.f};
  f32x4 acc[MI][NI];
  #pragma unroll
  for (int mi = 0; mi < MI; ++mi)
    #pragma unroll
    for (int ni = 0; ni < NI; ++ni) acc[mi][ni] = zero4;
  const int srow = lane >> 3;
  const int scol = ((lane & 7) ^ (lane >> 3)) * 8;
  auto stage = [&](int bf, int k0) {
    #pragma unroll
    for (int cc = 0; cc < ACH; ++cc) {
      int c = w * ACH + cc;
      gload16(A + (size_t)(bM + 8 * c + srow) * K + k0 + scol, (void*)(&As[bf][c * 512]));
    }
    #pragma unroll
    for (int cc = 0; cc < BCH; ++cc) {
      int c = w * BCH + cc;
      gload16(B + (size_t)(bN + 8 * c + srow) * K + k0 + scol, (void*)(&Bs[bf][c * 512]));
    }
  };
  const int kper = K / gridDim.z;
  const int kbase = blockIdx.z * kper;
  const int nt = kper / 64;
  stage(0, kbase);
  __syncthreads();
  int buf = 0;
  for (int t = 0; t < nt; ++t) {
    if (t + 1 < nt) stage(buf ^ 1, kbase + (t + 1) * 64);
    #pragma unroll
    for (int kk = 0; kk < 2; ++kk) {
      bf16x8 af[MI], bfr[NI];
      #pragma unroll
      for (int mi = 0; mi < MI; ++mi) {
        int row = wr * (BM / 2) + mi * 16 + l15;
        af[mi] = *(const bf16x8*)(&As[buf][row * 64 + (((kk * 4 + rq) ^ (row & 7)) * 8)]);
      }
      #pragma unroll
      for (int ni = 0; ni < NI; ++ni) {
        int row = wc * (BN / 2) + ni * 16 + l15;
        bfr[ni] = *(const bf16x8*)(&Bs[buf][row * 64 + (((kk * 4 + rq) ^ (row & 7)) * 8)]);
      }
      #pragma unroll
      for (int mi = 0; mi < MI; ++mi)
        #pragma unroll
        for (int ni = 0; ni < NI; ++ni)
          acc[mi][ni] = MFMA(af[mi], bfr[ni], acc[mi][ni]);
    }
    __syncthreads();
    buf ^= 1;
  }
  #pragma unroll
  for (int mi = 0; mi < MI; ++mi)
    #pragma unroll
    for (int ni = 0; ni < NI; ++ni)
      #pragma unroll
      for (int r = 0; r < 4; ++r) {
        int row = bM + wr * (BM / 2) + mi * 16 + 4 * rq + r;
        int col = bN + wc * (BN / 2) + ni * 16 + l15;
        if constexpr (EPI == 4) {
          outf[(size_t)blockIdx.z * M * N + (size_t)row * N + col] = acc[mi][ni][r];
        } else {
          float val = acc[mi][ni][r] + bias[col];
          if constexpr (EPI == 0) {
            outb[(size_t)row * N + col] = f2bf(val);
          } else if constexpr (EPI == 1) {
            outb[(size_t)row * N + col] = f2bf(gelu_f(val));
          } else if constexpr (EPI == 2) {
            outf[(size_t)row * N + col] = resid[(size_t)row * N + col] + val;
          } else {
            outf[(size_t)row * N + col] = val;
          }
        }
      }
}

// ---------------- sigmoid attention (m-split partials) ----------------
__global__ __launch_bounds__(256) void attn_kernel(const unsigned short* __restrict__ qkv,
                                                   float* __restrict__ po,
                                                   float* __restrict__ prs) {
  __shared__ unsigned short Ks[64 * 64];
  __shared__ unsigned short vt[64 * 72];
  __shared__ unsigned short pl[4][16 * 72];
  const int tid = threadIdx.x;
  const int w = tid >> 6, lane = tid & 63;
  const int l15 = lane & 15, rq = lane >> 4;
  const int b = blockIdx.y / NH, h = blockIdx.y % NH;
  const int n0 = blockIdx.x * 64;
  const int part = blockIdx.z;
  const unsigned short* base = qkv + (size_t)(b * NSEQ) * QKVN + h * HD;
  bf16x8 aq0, aq1;
  {
    const unsigned short* qp = base + (size_t)(n0 + w * 16 + l15) * QKVN + rq * 8;
    aq0 = *(const bf16x8*)qp;
    aq1 = *(const bf16x8*)(qp + 32);
  }
  float rs[4] = {0.f, 0.f, 0.f, 0.f};
  const f32x4 zero4 = {0.f, 0.f, 0.f, 0.f};
  f32x4 acco[4];
  #pragma unroll
  for (int j = 0; j < 4; ++j) acco[j] = zero4;
  unsigned short* plw = &pl[w][0];

  for (int mt = 0; mt < 4; ++mt) {
    const int m0 = part * 256 + mt * 64;
    __syncthreads();
    #pragma unroll
    for (int it = 0; it < 2; ++it) {
      int idx = tid + it * 256;
      int r = idx >> 3, c = idx & 7;
      bf16x8 kv = *(const bf16x8*)(base + 768 + (size_t)(m0 + r) * QKVN + c * 8);
      *(bf16x8*)(Ks + r * 64 + (c ^ (r & 7)) * 8) = kv;
      int cd = idx & 63, g = (idx >> 6) & 7;
      const unsigned short* vp = base + 1536 + (size_t)(m0 + g * 8) * QKVN + cd;
      bf16x8 vv;
      #pragma unroll
      for (int j = 0; j < 8; ++j) vv[j] = (short)vp[(size_t)j * QKVN];
      *(bf16x8*)(vt + cd * 72 + g * 8) = vv;
    }
    __syncthreads();
    #pragma unroll
    for (int ni = 0; ni < 4; ++ni) {
      int kr = ni * 16 + l15;
      bf16x8 bk0 = *(const bf16x8*)(Ks + kr * 64 + ((rq) ^ (kr & 7)) * 8);
      bf16x8 bk1 = *(const bf16x8*)(Ks + kr * 64 + ((rq + 4) ^ (kr & 7)) * 8);
      f32x4 z = zero4;
      z = MFMA(aq0, bk0, z);
      z = MFMA(aq1, bk1, z);
      #pragma unroll
      for (int r = 0; r < 4; ++r) {
        float p = sigmoid8(z[r]);
        rs[r] += p;
        plw[(4 * rq + r) * 72 + ni * 16 + l15] = f2bf(p);
      }
    }
    #pragma unroll
    for (int kk = 0; kk < 2; ++kk) {
      bf16x8 ap = *(const bf16x8*)(plw + l15 * 72 + kk * 32 + rq * 8);
      #pragma unroll
      for (int j2 = 0; j2 < 4; ++j2) {
        bf16x8 bvv = *(const bf16x8*)(vt + (j2 * 16 + l15) * 72 + kk * 32 + rq * 8);
        acco[j2] = MFMA(ap, bvv, acco[j2]);
      }
    }
  }
  #pragma unroll
  for (int m = 1; m < 16; m <<= 1)
    #pragma unroll
    for (int r = 0; r < 4; ++r) rs[r] += __shfl_xor(rs[r], m);
  float* pop = po + (size_t)part * MTOK * DM;
  #pragma unroll
  for (int j2 = 0; j2 < 4; ++j2)
    #pragma unroll
    for (int r = 0; r < 4; ++r) {
      int row = b * NSEQ + n0 + w * 16 + 4 * rq + r;
      int col = h * HD + j2 * 16 + l15;
      pop[(size_t)row * DM + col] = acco[j2][r];
    }
  if (l15 == 0) {
    #pragma unroll
    for (int r = 0; r < 4; ++r)
      prs[((size_t)part * (BB * NH) + blockIdx.y) * NSEQ + n0 + w * 16 + 4 * rq + r] = rs[r];
  }
}

// ---------------- combine attention partials -> bf16 ----------------
__global__ __launch_bounds__(256) void attn_combine(const float* __restrict__ po,
                                                    const float* __restrict__ prs,
                                                    unsigned short* __restrict__ attnbf) {
  int i = blockIdx.x * 256 + threadIdx.x;
  int e = i * 4;
  int row = e / DM, col = e % DM;
  int b = row >> 9, n = row & 511, h = col >> 6;
  float r0 = prs[((size_t)(b * NH + h)) * NSEQ + n];
  float r1 = prs[(size_t)(BB * NH) * NSEQ + ((size_t)(b * NH + h)) * NSEQ + n];
  float inv = 1.f / (r0 + r1 + 1e-6f);
  float4 p0 = *reinterpret_cast<const float4*>(po + e);
  float4 p1 = *reinterpret_cast<const float4*>(po + (size_t)MTOK * DM + e);
  ushort4 o;
  o.x = f2bf((p0.x + p1.x) * inv);
  o.y = f2bf((p0.y + p1.y) * inv);
  o.z = f2bf((p0.z + p1.z) * inv);
  o.w = f2bf((p0.w + p1.w) * inv);
  *reinterpret_cast<ushort4*>(attnbf + e) = o;
}

// ---------------- raw_w second projection ----------------
__global__ __launch_bounds__(128) void wr2_kernel(const unsigned short* __restrict__ h1,
                                                  const float* __restrict__ wr2,
                                                  const float* __restrict__ br2,
                                                  float* __restrict__ raww) {
  __shared__ float hrow[DR1];
  int row = blockIdx.x;
  const unsigned short* hp = h1 + (size_t)row * DR1;
  for (int c = threadIdx.x; c < DR1; c += 128) hrow[c] = bf2f(hp[c]);
  __syncthreads();
  int j = threadIdx.x;
  if (j < TH) {
    const float* wrow = wr2 + (size_t)j * DR1;
    float acc = 0.f;
    for (int c4 = 0; c4 < DR1 / 4; ++c4) {
      float4 hv = *reinterpret_cast<const float4*>(hrow + c4 * 4);
      float4 wv = *reinterpret_cast<const float4*>(wrow + c4 * 4);
      acc += hv.x * wv.x + hv.y * wv.y + hv.z * wv.z + hv.w * wv.w;
    }
    raww[(size_t)row * TH + j] = acc + br2[j];
  }
}

// ---------------- aggregation partials ----------------
__global__ __launch_bounds__(256) void agg_kernel(const unsigned short* __restrict__ qkv_all,
                                                  const float* __restrict__ raww,
                                                  float* __restrict__ part) {
  __shared__ unsigned short Ks[64 * 64];
  __shared__ unsigned short Qs[64 * 64];
  const int tid = threadIdx.x;
  const int w = tid >> 6, lane = tid & 63;
  const int l15 = lane & 15, rq = lane >> 4;
  const int z = blockIdx.z;
  const int l = z >> 2, b = z & 3;
  const int m0 = blockIdx.x * 64, nb = blockIdx.y * 64;
  const unsigned short* base = qkv_all + (size_t)l * MTOK * QKVN + (size_t)(b * NSEQ) * QKVN;
  const f32x4 zero4 = {0.f, 0.f, 0.f, 0.f};
  float acc[4][4];
  #pragma unroll
  for (int ni = 0; ni < 4; ++ni)
    #pragma unroll
    for (int r = 0; r < 4; ++r) acc[ni][r] = 0.f;
  for (int h = 0; h < NH; ++h) {
    __syncthreads();
    #pragma unroll
    for (int it = 0; it < 2; ++it) {
      int idx = tid + it * 256;
      int r = idx >> 3, c = idx & 7;
      bf16x8 kv = *(const bf16x8*)(base + (size_t)(m0 + r) * QKVN + 768 + h * HD + c * 8);
      *(bf16x8*)(Ks + r * 64 + (c ^ (r & 7)) * 8) = kv;
      bf16x8 qv = *(const bf16x8*)(base + (size_t)(nb + r) * QKVN + h * HD + c * 8);
      *(bf16x8*)(Qs + r * 64 + (c ^ (r & 7)) * 8) = qv;
    }
    __syncthreads();
    const int qr = w * 16 + l15;
    bf16x8 aq0 = *(const bf16x8*)(Qs + qr * 64 + ((rq) ^ (qr & 7)) * 8);
    bf16x8 aq1 = *(const bf16x8*)(Qs + qr * 64 + ((rq + 4) ^ (qr & 7)) * 8);
    float wl[4];
    #pragma unroll
    for (int r = 0; r < 4; ++r)
      wl[r] = raww[(size_t)(b * NSEQ + nb + w * 16 + 4 * rq + r) * TH + l * NH + h];
    #pragma unroll
    for (int ni = 0; ni < 4; ++ni) {
      int kr = ni * 16 + l15;
      bf16x8 bk0 = *(const bf16x8*)(Ks + kr * 64 + ((rq) ^ (kr & 7)) * 8);
      bf16x8 bk1 = *(const bf16x8*)(Ks + kr * 64 + ((rq + 4) ^ (kr & 7)) * 8);
      f32x4 zz = zero4;
      zz = MFMA(aq0, bk0, zz);
      zz = MFMA(aq1, bk1, zz);
      #pragma unroll
      for (int r = 0; r < 4; ++r) {
        acc[ni][r] += wl[r] * sigmoid8(zz[r]);
      }
    }
  }
  #pragma unroll
  for (int ni = 0; ni < 4; ++ni)
    #pragma unroll
    for (int r = 0; r < 4; ++r) {
      int n = nb + w * 16 + 4 * rq + r;
      part[((size_t)z * NSEQ + n) * NSEQ + m0 + ni * 16 + l15] = acc[ni][r];
    }
}

// ---------------- reduce partials over layers + bias + diag mask ----------------
__global__ __launch_bounds__(256) void agg_reduce(const float* __restrict__ part,
                                                  const float* __restrict__ agg_bias,
                                                  float* __restrict__ out) {
  int i = blockIdx.x * 256 + threadIdx.x;
  int e = i * 4;
  float4 s = {0.f, 0.f, 0.f, 0.f};
  #pragma unroll
  for (int l = 0; l < LAYERS; ++l) {
    float4 p = *reinterpret_cast<const float4*>(part + (size_t)l * BB * NSEQ * NSEQ + e);
    s.x += p.x; s.y += p.y; s.z += p.z; s.w += p.w;
  }
  int n = (e >> 9) & 511, m = e & 511;
  float ab = agg_bias[0];
  float4 o;
  o.x = (n == m)     ? ab : s.x + ab;
  o.y = (n == m + 1) ? ab : s.y + ab;
  o.z = (n == m + 2) ? ab : s.z + ab;
  o.w = (n == m + 3) ? ab : s.w + ab;
  *reinterpret_cast<float4*>(out + e) = o;
}

// ---------------- host ----------------
extern "C" void kernel_launch(void* const* d_in, const int* in_sizes, int n_in,
                              void* d_out, int out_size, void* d_ws, size_t ws_size,
                              hipStream_t stream) {
  const float* emb  = (const float*)d_in[0];
  const float* Win  = (const float*)d_in[1];
  const float* b_in = (const float*)d_in[2];
  const float* Wq   = (const float*)d_in[3];
  const float* bq   = (const float*)d_in[4];
  const float* Wk   = (const float*)d_in[5];
  const float* bk   = (const float*)d_in[6];
  const float* Wv   = (const float*)d_in[7];
  const float* bv   = (const float*)d_in[8];
  const float* Wo   = (const float*)d_in[9];
  const float* bo   = (const float*)d_in[10];
  const float* g1   = (const float*)d_in[11];
  const float* be1  = (const float*)d_in[12];
  const float* g2   = (const float*)d_in[13];
  const float* be2  = (const float*)d_in[14];
  const float* W1   = (const float*)d_in[15];
  const float* bf1  = (const float*)d_in[16];
  const float* W2   = (const float*)d_in[17];
  const float* bf2  = (const float*)d_in[18];
  const float* Wr1  = (const float*)d_in[19];
  const float* br1  = (const float*)d_in[20];
  const float* Wr2  = (const float*)d_in[21];
  const float* br2  = (const float*)d_in[22];
  const float* aggb = (const float*)d_in[23];
  float* out = (float*)d_out;
  (void)in_sizes; (void)n_in; (void)out_size; (void)ws_size;

  char* ws = (char*)d_ws;
  size_t off = 0;
  auto alloc = [&](size_t bytes) -> char* {
    char* p = ws + off;
    off += (bytes + 255) & ~(size_t)255;
    return p;
  };
  // persistent region (all-layer weights)
  unsigned short* qkvw6  = (unsigned short*)alloc((size_t)LAYERS * QKVN * DM * 2);
  float*          qkvb6  = (float*)alloc((size_t)LAYERS * QKVN * 4);
  unsigned short* wow6   = (unsigned short*)alloc((size_t)LAYERS * DM * DM * 2);
  unsigned short* w1w6   = (unsigned short*)alloc((size_t)LAYERS * DFF * DM * 2);
  unsigned short* w2w6   = (unsigned short*)alloc((size_t)LAYERS * DM * DFF * 2);
  unsigned short* winw   = (unsigned short*)alloc((size_t)DM * DM * 2);
  unsigned short* wr1w   = (unsigned short*)alloc((size_t)DR1 * DM * 2);
  unsigned short* h1bf   = (unsigned short*)alloc((size_t)MTOK * DR1 * 2);
  float*          raww   = (float*)alloc((size_t)MTOK * TH * 4);
  float*          prs    = (float*)alloc((size_t)2 * BB * NH * NSEQ * 4);
  float*          skbuf  = (float*)alloc((size_t)2 * MTOK * DM * 4);
  unsigned short* qkvall = (unsigned short*)alloc((size_t)LAYERS * MTOK * QKVN * 2);
  // scratch region
  char* scratch = alloc(0);
  unsigned short* embbf  = (unsigned short*)(scratch);
  float*          x      = (float*)(scratch + 3145728);
  unsigned short* nbf    = (unsigned short*)(scratch + 3145728 + 6291456);
  unsigned short* attnbf = (unsigned short*)(scratch + 3145728 + 6291456 + 3145728);
  char*           S      = scratch + 3145728 + 6291456 + 3145728 + 3145728;
  unsigned short* xbf    = (unsigned short*)(S + 12582912);
  float*          po     = (float*)S;
  unsigned short* ff1bf  = (unsigned short*)S;
  float*          part   = (float*)scratch;   // 25.2 MB, aliases dead early scratch

  // ALL converts in one dispatch: per-layer pieces (3456 blocks) + shared pieces
  // (emb 768 / Win 288 / Wr1 144 blocks beyond, on y=0/1/2).
  convert_all<<<dim3(3456 + 768, LAYERS), 256, 0, stream>>>(
      Wq, Wk, Wv, Wo, W1, W2, bq, bk, bv, emb, Win, Wr1,
      qkvw6, qkvb6, wow6, w1w6, w2w6, embbf, winw, wr1w);

  dim3 g768(DM / 64, MTOK / 64);        // (12,32)
  gemm_bt<64, 64, 3><<<g768, 256, 0, stream>>>(embbf, winw, b_in, nullptr, x, nullptr, MTOK, DM, DM);
  ln_kernel<<<512, 256, 0, stream>>>(x, g1, be1, nbf);   // layer-0 LN1

  for (int l = 0; l < LAYERS; ++l) {
    unsigned short* qkvl = qkvall + (size_t)l * MTOK * QKVN;
    dim3 gqkv(QKVN / 128, MTOK / 64);   // (18,32) BM=64,BN=128
    gemm_bt<64, 128, 0><<<gqkv, 256, 0, stream>>>(nbf, qkvw6 + (size_t)l * QKVN * DM,
                                                  qkvb6 + (size_t)l * QKVN, nullptr, nullptr,
                                                  qkvl, MTOK, QKVN, DM);
    attn_kernel<<<dim3(8, BB * NH, 2), 256, 0, stream>>>(qkvl, po, prs);
    attn_combine<<<(MTOK * DM / 4) / 256, 256, 0, stream>>>(po, prs, attnbf);
    gemm_bt<64, 64, 2><<<g768, 256, 0, stream>>>(attnbf, wow6 + (size_t)l * DM * DM,
                                                 bo + l * DM, x, x, nullptr, MTOK, DM, DM);
    ln_kernel<<<512, 256, 0, stream>>>(x, g2 + l * DM, be2 + l * DM, nbf);
    dim3 gff1(DFF / 128, MTOK / 64);    // (24,32) BM=64,BN=128
    gemm_bt<64, 128, 1><<<gff1, 256, 0, stream>>>(nbf, w1w6 + (size_t)l * DFF * DM,
                                                  bf1 + l * DFF, nullptr, nullptr, ff1bf,
                                                  MTOK, DFF, DM);
    dim3 gff2(DM / 64, MTOK / 64, 2);   // (12,32,2) split-K
    gemm_bt<64, 64, 4><<<gff2, 256, 0, stream>>>(ff1bf, w2w6 + (size_t)l * DM * DFF,
                                                 nullptr, nullptr, skbuf, nullptr, MTOK, DM, DFF);
    if (l < LAYERS - 1) {
      ff2_ln<<<512, 256, 0, stream>>>(skbuf, bf2 + l * DM, x,
                                      g1 + (l + 1) * DM, be1 + (l + 1) * DM, nbf, 0);
    } else {
      ff2_ln<<<512, 256, 0, stream>>>(skbuf, bf2 + l * DM, x, g1, be1, xbf, 1);
    }
  }

  dim3 gr1(DR1 / 64, MTOK / 64);        // (6,32)
  gemm_bt<64, 64, 1><<<gr1, 256, 0, stream>>>(xbf, wr1w, br1, nullptr, nullptr, h1bf, MTOK, DR1, DM);
  wr2_kernel<<<MTOK, 128, 0, stream>>>(h1bf, Wr2, br2, raww);
  agg_kernel<<<dim3(8, 8, LAYERS * BB), 256, 0, stream>>>(qkvall, raww, part);
  agg_reduce<<<(BB * NSEQ * NSEQ / 4) / 256, 256, 0, stream>>>(part, aggb, out);
}